// Round 5
// baseline (434.894 us; speedup 1.0000x reference)
//
#include <hip/hip_runtime.h>
#include <hip/hip_bf16.h>

// Problem constants
#define BATCH 32
#define CIN   256
#define COUT  256
#define HH    56
#define HP    58      // padded
#define NEXP  5
#define HID   65

// Workspace layout (bytes)
#define OFF_S     0                         // 32*256*4      = 32768
#define OFF_ATTN  32768                     // 32*5*4        = 640
#define OFF_WAL   65536                     // 5*9*256*256*4 = 11796480
#define OFF_AGGW  (12u*1024u*1024u)         // 32*9*256*256*2 = 37748736
#define OFF_XPAD  (48u*1024u*1024u)         // 32*58*58*256*2 = 55115776
// total ~ 101 MB

typedef __bf16 bf16x8 __attribute__((ext_vector_type(8)));
typedef float  f32x4  __attribute__((ext_vector_type(4)));

__device__ __forceinline__ unsigned short f2bf(float f) {
    unsigned int u = __float_as_uint(f);
    unsigned int r = (u + 0x7FFFu + ((u >> 16) & 1u)) >> 16;
    return (unsigned short)r;
}

#define AS1 __attribute__((address_space(1)))
#define AS3 __attribute__((address_space(3)))
__device__ __forceinline__ void gl_lds16(const unsigned short* g, unsigned short* l) {
    __builtin_amdgcn_global_load_lds((const AS1 void*)g, (AS3 void*)l, 16, 0, 0);
}

// ---------------------------------------------------------------------------
// k2: x (NCHW f32) -> xpad interior (NHWC bf16), fused pool partials + border
// grid (28, 2, 32): (row-pair, channel-half, sample). block 256.
#define XLP 132   // lds channel pitch (ushort); %4==0 so uint2 reads align
__global__ void xprep_kernel(const float* __restrict__ x,
                             unsigned short* __restrict__ xpad,
                             float* __restrict__ s) {
    const int y0 = blockIdx.x * 2, c0 = blockIdx.y * 128, b = blockIdx.z;
    const int tid = threadIdx.x, lane = tid & 63, wg = tid >> 6;
    __shared__ unsigned short lds[2 * HH * XLP];   // [row][x][c<128]

    // fused border zeroing (1-px frame of xpad, this block's 128 channels)
    {
        const uint4 z = make_uint4(0, 0, 0, 0);
        if (blockIdx.x == 0) {          // padded row 0
            uint4* p = (uint4*)(xpad + (size_t)(b * HP * HP) * 256 + c0);
            for (int i = tid; i < HP * 16; i += 256)   // 58 cols x 16 uint4
                p[(i >> 4) * 32 + (i & 15)] = z;
        }
        if (blockIdx.x == 27) {         // padded row 57
            uint4* p = (uint4*)(xpad + (size_t)((b * HP + 57) * HP) * 256 + c0);
            for (int i = tid; i < HP * 16; i += 256)
                p[(i >> 4) * 32 + (i & 15)] = z;
        }
        // left/right edges of padded rows y0+1, y0+2
        if (tid < 64) {
            const int r = y0 + 1 + (tid >> 5);
            const int cc = ((tid >> 4) & 1) * 57;
            uint4* p = (uint4*)(xpad + (size_t)((b * HP + r) * HP + cc) * 256 + c0);
            p[tid & 15] = z;
        }
    }

    #pragma unroll 2
    for (int cc = wg; cc < 128; cc += 4) {
        if (lane < HH) {
            const float2 v = *(const float2*)&x[
                (size_t)((b * 256 + c0 + cc) * HH + y0) * HH + lane * 2];
            const int p = lane * 2;
            const int r0 = p / HH, x0 = p - r0 * HH;
            const int q = p + 1;
            const int r1 = q / HH, x1 = q - r1 * HH;
            lds[(r0 * HH + x0) * XLP + cc] = f2bf(v.x);
            lds[(r1 * HH + x1) * XLP + cc] = f2bf(v.y);
        }
    }
    __syncthreads();
    {   // pooling partial: thread -> (row, channel)
        const int r = tid >> 7, c = tid & 127;
        float sum = 0.f;
        for (int xx = 0; xx < HH; ++xx) {
            const unsigned int u = lds[(r * HH + xx) * XLP + c];
            sum += __uint_as_float(u << 16);
        }
        atomicAdd(&s[b * 256 + c0 + c], sum);
    }
    // write-out: 2 rows x 56 x x 128 ch, 8 B per store
    for (int i = tid; i < 2 * HH * 32; i += 256) {
        const int r = (i >= HH * 32) ? 1 : 0;
        const int rem = i - r * HH * 32;
        const int xx = rem >> 5, cq = (rem & 31) * 4;
        const uint2 v = *(const uint2*)&lds[(r * HH + xx) * XLP + cq];
        *(uint2*)(xpad + (size_t)(((b * HP + y0 + r + 1) * HP + (xx + 1))) * 256
                  + c0 + cq) = v;
    }
}

// ---------------------------------------------------------------------------
// k3: attention MLP, parallelized over (h, c-half).  grid 32, block 256
__global__ void attn_kernel(const float* __restrict__ s,
                            const float* __restrict__ w1,
                            const float* __restrict__ w2,
                            const float* __restrict__ b2,
                            float* __restrict__ attn) {
    const int b = blockIdx.x, tid = threadIdx.x;
    __shared__ float sm[256];
    __shared__ float part[130];
    __shared__ float hm[HID];
    sm[tid] = s[b * 256 + tid] * (1.f / 3136.f);
    __syncthreads();
    if (tid < 130) {
        const int h = (tid >= 65) ? tid - 65 : tid;
        const int base = (tid >= 65) ? 128 : 0;
        float acc = 0.f;
        #pragma unroll 4
        for (int c = 0; c < 128; ++c) acc += sm[base + c] * w1[h * 256 + base + c];
        part[tid] = acc;
    }
    __syncthreads();
    if (tid < HID) hm[tid] = fmaxf(part[tid] + part[tid + 65], 0.f);
    __syncthreads();
    if (tid < NEXP) {
        float acc = b2[tid];
        for (int j = 0; j < HID; ++j) acc += hm[j] * w2[tid * HID + j];
        attn[b * NEXP + tid] = 1.f / (1.f + expf(-acc));
    }
}

// ---------------------------------------------------------------------------
// k4: w_aligned[e,t,j,i] = sum_o align[e,j,o] * W[e,o,i*9+t]   (fp32)
// grid (18, 4, 5): n-tile(128), j-tile(64), e.  block 256.
__global__ void align_kernel(const float* __restrict__ am,
                             const float* __restrict__ w,
                             float* __restrict__ wal) {
    const int nt = blockIdx.x, jt = blockIdx.y, e = blockIdx.z;
    const int tid = threadIdx.x;
    const int tj = tid >> 5, tn = tid & 31;
    __shared__ float At[64][33];
    __shared__ float Wt[32][128];
    float acc[8][4];
    #pragma unroll
    for (int a = 0; a < 8; ++a)
        #pragma unroll
        for (int c = 0; c < 4; ++c) acc[a][c] = 0.f;

    for (int o0 = 0; o0 < 256; o0 += 32) {
        {   // stage align tile 64x32
            const int row = tid >> 2, col = (tid & 3) * 8;
            const float* src = am + (size_t)((e * 256) + jt * 64 + row) * 256 + o0 + col;
            float4 v0 = *(const float4*)(src);
            float4 v1 = *(const float4*)(src + 4);
            *(float4*)&At[row][col] = v0;
            *(float4*)&At[row][col + 4] = v1;
        }
        {   // stage W tile 32x128
            const int row = tid >> 3, col = (tid & 7) * 16;
            const float* src = w + (size_t)((e * 256) + o0 + row) * 2304 + nt * 128 + col;
            #pragma unroll
            for (int q = 0; q < 4; ++q)
                *(float4*)&Wt[row][col + q * 4] = *(const float4*)(src + q * 4);
        }
        __syncthreads();
        for (int k = 0; k < 32; ++k) {
            float wv[4];
            #pragma unroll
            for (int c = 0; c < 4; ++c) wv[c] = Wt[k][tn * 4 + c];
            #pragma unroll
            for (int a = 0; a < 8; ++a) {
                const float av = At[tj * 8 + a][k];
                #pragma unroll
                for (int c = 0; c < 4; ++c) acc[a][c] += av * wv[c];
            }
        }
        __syncthreads();
    }
    #pragma unroll
    for (int a = 0; a < 8; ++a) {
        const int j = jt * 64 + tj * 8 + a;
        #pragma unroll
        for (int c = 0; c < 4; ++c) {
            const int n = nt * 128 + tn * 4 + c;
            const int t = n % 9, i = n / 9;
            wal[(size_t)(((e * 9 + t) * 256 + j)) * 256 + i] = acc[a][c];
        }
    }
}

// ---------------------------------------------------------------------------
// k5: agg_w[b,t,j,i] (bf16) = sum_e attn[b,e] * wal[e,t,j,i]
// grid 576: t = bx>>6, j-quad = bx&63.  block 256: jl = tid>>6, i4 = (tid&63)*4
__global__ void agg_kernel(const float* __restrict__ wal,
                           const float* __restrict__ attn,
                           unsigned short* __restrict__ aggw) {
    const int t = blockIdx.x >> 6;
    const int j = (blockIdx.x & 63) * 4 + (threadIdx.x >> 6);
    const int i = (threadIdx.x & 63) * 4;
    __shared__ float at[BATCH * NEXP];
    if (threadIdx.x < BATCH * NEXP) at[threadIdx.x] = attn[threadIdx.x];
    float4 wv[NEXP];
    #pragma unroll
    for (int e = 0; e < NEXP; ++e)
        wv[e] = *(const float4*)&wal[(size_t)(((e * 9 + t) * 256 + j)) * 256 + i];
    __syncthreads();
    for (int b = 0; b < BATCH; ++b) {
        float4 acc = make_float4(0.f, 0.f, 0.f, 0.f);
        #pragma unroll
        for (int e = 0; e < NEXP; ++e) {
            const float a = at[b * NEXP + e];
            acc.x += a * wv[e].x; acc.y += a * wv[e].y;
            acc.z += a * wv[e].z; acc.w += a * wv[e].w;
        }
        uint2 pk;
        pk.x = (unsigned)f2bf(acc.x) | ((unsigned)f2bf(acc.y) << 16);
        pk.y = (unsigned)f2bf(acc.z) | ((unsigned)f2bf(acc.w) << 16);
        *(uint2*)&aggw[(size_t)(((b * 9 + t) * 256 + j)) * 256 + i] = pk;
    }
}

// ---------------------------------------------------------------------------
// k6 v5 (resubmit; R4 failure was container-level, kernel re-audited clean):
// implicit-GEMM conv, concurrency-first.
// R3 post-mortem: per-phase time == LDS-cycles + MFMA-cycles SUMMED (6880 vs
// 3259+3700 modeled) -- 8 barrier-locked waves at 2/SIMD surge LDS then
// matrix with zero overlap. v5 fixes via 3 INDEPENDENT blocks/CU drifting
// out of phase, so one block's LDS burst hides under another's MFMAs:
//  - wave tile back to 64 couts x 64 px (4mt x 4nt, acc=64; R2 measured 64
//    VGPR + 64 AGPR = 128 unified -> 3 waves/SIMD fits easily)
//  - block = 256 thr = 4 waves (one per cout-group), region 8c x 8r
//  - A staged per-tap via global_load_lds: 2 x 1024 units (16 KB) dbuf
//  - B slab 10r x 10c x 32ch: 2 x 400 units (6.4 KB) dbuf per K-step
//  - LDS total 45568 B -> 3 blocks/CU (12 waves, Occupancy ~37%)
// Grid 1568 = 8 XCD x 196 slots, sample-major per XCD (b = xcd*4 + slot/49)
// so ~2 samples (2.4 MB aggw) stay L2-resident per XCD for the A-DMA.
// Sync: proven R3 pattern -- issue next-tap DMA into ^1 buffer, compute
// current, one __syncthreads per tap-phase (72 phases).
// Bank math: A-read unit%8 = 4*(ln&1)+quad -> 8 touches/bank (minimum);
// B row pitch 640B %128==0 -> 8 touches/bank (minimum).
__global__ __launch_bounds__(256, 3) void conv_kernel(
        const unsigned short* __restrict__ xpad,
        const unsigned short* __restrict__ aggw,
        float* __restrict__ out) {
    const int blk = blockIdx.x;
    const int xcd = blk & 7, slot = blk >> 3;       // slot 0..195
    const int b = xcd * 4 + slot / 49;
    const int pos = slot % 49;
    const int y0 = (pos / 7) * 8, x0 = (pos % 7) * 8;   // output region origin
    const int tid = threadIdx.x;
    const int wm = tid >> 6, lane = tid & 63;
    const int quad = lane >> 4, ln = lane & 15;

    __shared__ unsigned short ldsA[2 * 8192];   // 2 x 1024 units x 16B = 32 KB
    __shared__ unsigned short ldsB[2 * 3200];   // 2 x  400 units x 16B = 12.8 KB

    f32x4 acc[4][4];
    #pragma unroll
    for (int mt = 0; mt < 4; ++mt)
        #pragma unroll
        for (int nt = 0; nt < 4; ++nt) acc[mt][nt] = (f32x4){0.f, 0.f, 0.f, 0.f};

    // B-frag base byte offsets (kx=0,ky=0): px row=(ln>>3)+nt*2, col=ln&7
    int nb[4];
    #pragma unroll
    for (int nt = 0; nt < 4; ++nt)
        nb[nt] = ((((ln >> 3) + nt * 2) * 40 + (ln & 7) * 4 + quad)) * 16;

    // A-frag base byte offset: unit = cout*4 + quad, cout = wm*64 + mt*16 + ln
    const int abase = wm * 4096 + (ln * 4 + quad) * 16;

    // A staging descriptors: 1024 units = 4 x 256; u = tid + k*256
    // unit u -> cout = u>>2, sub = u&3
    const unsigned short* aspb;   // base for (tap=0, c0=0)
    int aldsu[4];
    {
        aspb = aggw + (size_t)(b * 9) * 65536;
        #pragma unroll
        for (int k = 0; k < 4; ++k) aldsu[k] = (tid + k * 256) * 8;
    }
    // per-thread A src offset within a tap: cout*256 + sub*8
    int asrc[4];
    #pragma unroll
    for (int k = 0; k < 4; ++k) {
        const int u = tid + k * 256;
        asrc[k] = (u >> 2) * 256 + (u & 3) * 8;
    }

    // B staging descriptors: 400 units; k=0 all 256 thr, k=1 tid<144
    const unsigned short* bsp[2];
    int bldsu[2];
    #pragma unroll
    for (int k = 0; k < 2; ++k) {
        int u = tid + k * 256; if (u > 399) u = 399;
        const int r = u / 40, rem = u - r * 40;
        const int c = rem >> 2, sub = rem & 3;
        bsp[k] = xpad + (size_t)(((b * HP + y0 + r) * HP + x0 + c)) * 256 + sub * 8;
        bldsu[k] = u * 8;
    }

    // prologue: stage A(c0=0, tap=0) -> bufA0, B(c0=0) -> bufB0
    #pragma unroll
    for (int k = 0; k < 4; ++k) gl_lds16(aspb + asrc[k], ldsA + aldsu[k]);
    gl_lds16(bsp[0], ldsB + bldsu[0]);
    if (tid < 144) gl_lds16(bsp[1], ldsB + bldsu[1]);
    __syncthreads();

    int pa = 0, pb = 0;
    #pragma unroll 1
    for (int c0 = 0; c0 < 256; c0 += 32) {
        #pragma unroll
        for (int tap = 0; tap < 9; ++tap) {
            // issue next-tap A-DMA into the other A buffer
            if (!(c0 == 224 && tap == 8)) {
                const int ntap = (tap == 8) ? 0 : tap + 1;
                const int nc0 = (tap == 8) ? c0 + 32 : c0;
                const unsigned short* srcA = aspb + ntap * 65536 + nc0;
                unsigned short* dA = ldsA + (pa ^ 1) * 8192;
                #pragma unroll
                for (int k = 0; k < 4; ++k) gl_lds16(srcA + asrc[k], dA + aldsu[k]);
            }
            // mid K-step: prefetch next c0's B slab
            if (tap == 4 && c0 < 224) {
                unsigned short* dB = ldsB + (pb ^ 1) * 3200;
                gl_lds16(bsp[0] + c0 + 32, dB + bldsu[0]);
                if (tid < 144) gl_lds16(bsp[1] + c0 + 32, dB + bldsu[1]);
            }
            // compute tap (ky = tap/3, kx = tap%3 -- static by unroll)
            const int ky = tap / 3, kx = tap % 3;
            const char* lA = (const char*)ldsA + pa * 16384;
            const char* lB = (const char*)ldsB + pb * 6400;
            bf16x8 a[4];
            #pragma unroll
            for (int mt = 0; mt < 4; ++mt)
                a[mt] = *(const bf16x8*)(lA + mt * 1024 + abase);
            #pragma unroll
            for (int nt = 0; nt < 4; ++nt) {
                const bf16x8 bf = *(const bf16x8*)(lB +
                    nb[nt] + (ky * 40 + kx * 4) * 16);
                #pragma unroll
                for (int mt = 0; mt < 4; ++mt)
                    acc[mt][nt] = __builtin_amdgcn_mfma_f32_16x16x32_bf16(
                        a[mt], bf, acc[mt][nt], 0, 0, 0);
            }
            __syncthreads();
            pa ^= 1;
        }
        pb ^= 1;
    }

    // epilogue: C/D layout col(n)=lane&15 -> pixel, row(m)=quad*4+reg -> cout
    #pragma unroll
    for (int mt = 0; mt < 4; ++mt) {
        #pragma unroll
        for (int nt = 0; nt < 4; ++nt) {
            const int yy = y0 + (ln >> 3) + nt * 2;
            const int xx = x0 + (ln & 7);
            #pragma unroll
            for (int r = 0; r < 4; ++r) {
                const int cout = wm * 64 + mt * 16 + quad * 4 + r;
                out[(size_t)(((b * 256 + cout) * HH + yy)) * HH + xx] = acc[mt][nt][r];
            }
        }
    }
}

// ---------------------------------------------------------------------------
extern "C" void kernel_launch(void* const* d_in, const int* in_sizes, int n_in,
                              void* d_out, int out_size, void* d_ws, size_t ws_size,
                              hipStream_t stream) {
    const float* x      = (const float*)d_in[0];
    const float* weight = (const float*)d_in[1];
    const float* am     = (const float*)d_in[2];
    const float* w1     = (const float*)d_in[3];
    const float* w2     = (const float*)d_in[4];
    const float* b2     = (const float*)d_in[5];
    float* out = (float*)d_out;
    char* ws = (char*)d_ws;

    float* s             = (float*)(ws + OFF_S);
    float* attn          = (float*)(ws + OFF_ATTN);
    float* wal           = (float*)(ws + OFF_WAL);
    unsigned short* aggw = (unsigned short*)(ws + OFF_AGGW);
    unsigned short* xpad = (unsigned short*)(ws + OFF_XPAD);

    hipMemsetAsync(s, 0, BATCH * 256 * sizeof(float), stream);
    xprep_kernel<<<dim3(28, 2, BATCH), 256, 0, stream>>>(x, xpad, s);
    attn_kernel<<<BATCH, 256, 0, stream>>>(s, w1, w2, b2, attn);
    align_kernel<<<dim3(18, 4, NEXP), 256, 0, stream>>>(am, weight, wal);
    agg_kernel<<<576, 256, 0, stream>>>(wal, attn, aggw);
    conv_kernel<<<1568, 256, 0, stream>>>(xpad, aggw, out);
}

// Round 6
// 387.367 us; speedup vs baseline: 1.1227x; 1.1227x over previous
//
#include <hip/hip_runtime.h>
#include <hip/hip_bf16.h>

// Problem constants
#define BATCH 32
#define CIN   256
#define COUT  256
#define HH    56
#define HP    58      // padded
#define NEXP  5
#define HID   65

// Workspace layout (bytes)
#define OFF_S     0                         // 32*256*4      = 32768
#define OFF_ATTN  32768                     // 32*5*4        = 640
#define OFF_WAL   65536                     // 5*9*256*256*4 = 11796480
#define OFF_AGGW  (12u*1024u*1024u)         // 32*9*256*256*2 = 37748736
#define OFF_XPAD  (48u*1024u*1024u)         // 32*58*58*256*2 = 55115776
// total ~ 101 MB

typedef __bf16 bf16x8 __attribute__((ext_vector_type(8)));
typedef float  f32x4  __attribute__((ext_vector_type(4)));

__device__ __forceinline__ unsigned short f2bf(float f) {
    unsigned int u = __float_as_uint(f);
    unsigned int r = (u + 0x7FFFu + ((u >> 16) & 1u)) >> 16;
    return (unsigned short)r;
}

#define AS1 __attribute__((address_space(1)))
#define AS3 __attribute__((address_space(3)))
__device__ __forceinline__ void gl_lds16(const unsigned short* g, unsigned short* l) {
    __builtin_amdgcn_global_load_lds((const AS1 void*)g, (AS3 void*)l, 16, 0, 0);
}

// ---------------------------------------------------------------------------
// k2: x (NCHW f32) -> xpad interior (NHWC bf16), fused pool partials + border
// grid (28, 2, 32): (row-pair, channel-half, sample). block 256.
#define XLP 132   // lds channel pitch (ushort); %4==0 so uint2 reads align
__global__ void xprep_kernel(const float* __restrict__ x,
                             unsigned short* __restrict__ xpad,
                             float* __restrict__ s) {
    const int y0 = blockIdx.x * 2, c0 = blockIdx.y * 128, b = blockIdx.z;
    const int tid = threadIdx.x, lane = tid & 63, wg = tid >> 6;
    __shared__ unsigned short lds[2 * HH * XLP];   // [row][x][c<128]

    // fused border zeroing (1-px frame of xpad, this block's 128 channels)
    {
        const uint4 z = make_uint4(0, 0, 0, 0);
        if (blockIdx.x == 0) {          // padded row 0
            uint4* p = (uint4*)(xpad + (size_t)(b * HP * HP) * 256 + c0);
            for (int i = tid; i < HP * 16; i += 256)   // 58 cols x 16 uint4
                p[(i >> 4) * 32 + (i & 15)] = z;
        }
        if (blockIdx.x == 27) {         // padded row 57
            uint4* p = (uint4*)(xpad + (size_t)((b * HP + 57) * HP) * 256 + c0);
            for (int i = tid; i < HP * 16; i += 256)
                p[(i >> 4) * 32 + (i & 15)] = z;
        }
        // left/right edges of padded rows y0+1, y0+2
        if (tid < 64) {
            const int r = y0 + 1 + (tid >> 5);
            const int cc = ((tid >> 4) & 1) * 57;
            uint4* p = (uint4*)(xpad + (size_t)((b * HP + r) * HP + cc) * 256 + c0);
            p[tid & 15] = z;
        }
    }

    #pragma unroll 2
    for (int cc = wg; cc < 128; cc += 4) {
        if (lane < HH) {
            const float2 v = *(const float2*)&x[
                (size_t)((b * 256 + c0 + cc) * HH + y0) * HH + lane * 2];
            const int p = lane * 2;
            const int r0 = p / HH, x0 = p - r0 * HH;
            const int q = p + 1;
            const int r1 = q / HH, x1 = q - r1 * HH;
            lds[(r0 * HH + x0) * XLP + cc] = f2bf(v.x);
            lds[(r1 * HH + x1) * XLP + cc] = f2bf(v.y);
        }
    }
    __syncthreads();
    {   // pooling partial: thread -> (row, channel)
        const int r = tid >> 7, c = tid & 127;
        float sum = 0.f;
        for (int xx = 0; xx < HH; ++xx) {
            const unsigned int u = lds[(r * HH + xx) * XLP + c];
            sum += __uint_as_float(u << 16);
        }
        atomicAdd(&s[b * 256 + c0 + c], sum);
    }
    // write-out: 2 rows x 56 x x 128 ch, 8 B per store
    for (int i = tid; i < 2 * HH * 32; i += 256) {
        const int r = (i >= HH * 32) ? 1 : 0;
        const int rem = i - r * HH * 32;
        const int xx = rem >> 5, cq = (rem & 31) * 4;
        const uint2 v = *(const uint2*)&lds[(r * HH + xx) * XLP + cq];
        *(uint2*)(xpad + (size_t)(((b * HP + y0 + r + 1) * HP + (xx + 1))) * 256
                  + c0 + cq) = v;
    }
}

// ---------------------------------------------------------------------------
// k3: attention MLP, parallelized over (h, c-half).  grid 32, block 256
__global__ void attn_kernel(const float* __restrict__ s,
                            const float* __restrict__ w1,
                            const float* __restrict__ w2,
                            const float* __restrict__ b2,
                            float* __restrict__ attn) {
    const int b = blockIdx.x, tid = threadIdx.x;
    __shared__ float sm[256];
    __shared__ float part[130];
    __shared__ float hm[HID];
    sm[tid] = s[b * 256 + tid] * (1.f / 3136.f);
    __syncthreads();
    if (tid < 130) {
        const int h = (tid >= 65) ? tid - 65 : tid;
        const int base = (tid >= 65) ? 128 : 0;
        float acc = 0.f;
        #pragma unroll 4
        for (int c = 0; c < 128; ++c) acc += sm[base + c] * w1[h * 256 + base + c];
        part[tid] = acc;
    }
    __syncthreads();
    if (tid < HID) hm[tid] = fmaxf(part[tid] + part[tid + 65], 0.f);
    __syncthreads();
    if (tid < NEXP) {
        float acc = b2[tid];
        for (int j = 0; j < HID; ++j) acc += hm[j] * w2[tid * HID + j];
        attn[b * NEXP + tid] = 1.f / (1.f + expf(-acc));
    }
}

// ---------------------------------------------------------------------------
// k4: w_aligned[e,t,j,i] = sum_o align[e,j,o] * W[e,o,i*9+t]   (fp32)
// grid (18, 4, 5): n-tile(128), j-tile(64), e.  block 256.
__global__ void align_kernel(const float* __restrict__ am,
                             const float* __restrict__ w,
                             float* __restrict__ wal) {
    const int nt = blockIdx.x, jt = blockIdx.y, e = blockIdx.z;
    const int tid = threadIdx.x;
    const int tj = tid >> 5, tn = tid & 31;
    __shared__ float At[64][33];
    __shared__ float Wt[32][128];
    float acc[8][4];
    #pragma unroll
    for (int a = 0; a < 8; ++a)
        #pragma unroll
        for (int c = 0; c < 4; ++c) acc[a][c] = 0.f;

    for (int o0 = 0; o0 < 256; o0 += 32) {
        {   // stage align tile 64x32
            const int row = tid >> 2, col = (tid & 3) * 8;
            const float* src = am + (size_t)((e * 256) + jt * 64 + row) * 256 + o0 + col;
            float4 v0 = *(const float4*)(src);
            float4 v1 = *(const float4*)(src + 4);
            *(float4*)&At[row][col] = v0;
            *(float4*)&At[row][col + 4] = v1;
        }
        {   // stage W tile 32x128
            const int row = tid >> 3, col = (tid & 7) * 16;
            const float* src = w + (size_t)((e * 256) + o0 + row) * 2304 + nt * 128 + col;
            #pragma unroll
            for (int q = 0; q < 4; ++q)
                *(float4*)&Wt[row][col + q * 4] = *(const float4*)(src + q * 4);
        }
        __syncthreads();
        for (int k = 0; k < 32; ++k) {
            float wv[4];
            #pragma unroll
            for (int c = 0; c < 4; ++c) wv[c] = Wt[k][tn * 4 + c];
            #pragma unroll
            for (int a = 0; a < 8; ++a) {
                const float av = At[tj * 8 + a][k];
                #pragma unroll
                for (int c = 0; c < 4; ++c) acc[a][c] += av * wv[c];
            }
        }
        __syncthreads();
    }
    #pragma unroll
    for (int a = 0; a < 8; ++a) {
        const int j = jt * 64 + tj * 8 + a;
        #pragma unroll
        for (int c = 0; c < 4; ++c) {
            const int n = nt * 128 + tn * 4 + c;
            const int t = n % 9, i = n / 9;
            wal[(size_t)(((e * 9 + t) * 256 + j)) * 256 + i] = acc[a][c];
        }
    }
}

// ---------------------------------------------------------------------------
// k5: agg_w[b,t,j,i] (bf16) = sum_e attn[b,e] * wal[e,t,j,i]
// grid 576: t = bx>>6, j-quad = bx&63.  block 256: jl = tid>>6, i4 = (tid&63)*4
__global__ void agg_kernel(const float* __restrict__ wal,
                           const float* __restrict__ attn,
                           unsigned short* __restrict__ aggw) {
    const int t = blockIdx.x >> 6;
    const int j = (blockIdx.x & 63) * 4 + (threadIdx.x >> 6);
    const int i = (threadIdx.x & 63) * 4;
    __shared__ float at[BATCH * NEXP];
    if (threadIdx.x < BATCH * NEXP) at[threadIdx.x] = attn[threadIdx.x];
    float4 wv[NEXP];
    #pragma unroll
    for (int e = 0; e < NEXP; ++e)
        wv[e] = *(const float4*)&wal[(size_t)(((e * 9 + t) * 256 + j)) * 256 + i];
    __syncthreads();
    for (int b = 0; b < BATCH; ++b) {
        float4 acc = make_float4(0.f, 0.f, 0.f, 0.f);
        #pragma unroll
        for (int e = 0; e < NEXP; ++e) {
            const float a = at[b * NEXP + e];
            acc.x += a * wv[e].x; acc.y += a * wv[e].y;
            acc.z += a * wv[e].z; acc.w += a * wv[e].w;
        }
        uint2 pk;
        pk.x = (unsigned)f2bf(acc.x) | ((unsigned)f2bf(acc.y) << 16);
        pk.y = (unsigned)f2bf(acc.z) | ((unsigned)f2bf(acc.w) << 16);
        *(uint2*)&aggw[(size_t)(((b * 9 + t) * 256 + j)) * 256 + i] = pk;
    }
}

// ---------------------------------------------------------------------------
// k6 v6: implicit-GEMM conv -- fat wave tiles + 2 independent blocks/CU.
// History: R3 (1 blk/CU, fat phases) = LDS/MFMA serialized (137 us);
// v5 (3 blk/CU, thin phases) = per-phase DMA-starved (190 us). v6 combines:
//  - wave tile 64 couts x 112 px (4mt x 7nt, acc=112 -> ~240 unified regs,
//    2 waves/SIMD cap -- the R1-proven shape)
//  - block 256 thr = 4 waves = 2 cout-groups (wm) x 2 px-halves (wp)
//    -> block covers 128 couts x 224 px (8 cols x 28 rows)
//  - A staged per tap for THIS block's 128 couts: 8 KB, double-buffered
//  - B slab 30r x 10c x 32cin: 19.2 KB, double-buffered
//  - LDS 54.8 KB -> 2 blocks/CU; each SIMD holds 1 wave from EACH block, so
//    one block's barrier-drain/LDS burst is covered by the other's MFMAs.
// Per-CU phase-pair budget: MFMA 2x543 = 1086 cyc; A-DMA 16 KB at the
// R3-measured >=15 B/cyc sustained rate ~= 1070 cyc; LDS reads 88 KB ~= 790
// cyc -- balanced, overlapping pipes.
// Grid 896 = 8 XCD x (4 samples x 28 slots); sample-major per XCD keeps the
// ~2.7 MB aggw working set L2-resident.
// Sync: exactly the v5-proven pattern (issue-next -> compute -> syncthreads).
// Bank math: A-frag slot%8 = 4*(ln&1)+quad -> 8 touches/bank (minimum);
// B row pitch 640B %128==0 -> 8 touches/bank (minimum).
__global__ __launch_bounds__(256, 2) void conv_kernel(
        const unsigned short* __restrict__ xpad,
        const unsigned short* __restrict__ aggw,
        float* __restrict__ out) {
    const int blk = blockIdx.x;
    const int xcd = blk & 7, slot = blk >> 3;       // slot 0..111
    const int b = xcd * 4 + slot / 28;
    const int rem = slot % 28;
    const int ch = rem & 1;                         // cout half (128)
    const int pos = rem >> 1;                       // 0..13
    const int x0 = (pos >> 1) * 8;                  // 7 col strips
    const int y0 = (pos & 1) * 28;                  // 2 row strips
    const int tid = threadIdx.x;
    const int w = tid >> 6, lane = tid & 63;
    const int wm = w & 1, wp = w >> 1;              // cout-group, px-half
    const int quad = lane >> 4, ln = lane & 15;

    __shared__ unsigned short ldsA[2 * 4096];   // 2 x 512 units x 16B = 16 KB
    __shared__ unsigned short ldsB[2 * 9600];   // 2 x 1200 units x 16B = 38.4 KB

    f32x4 acc[4][7];
    #pragma unroll
    for (int mt = 0; mt < 4; ++mt)
        #pragma unroll
        for (int nt = 0; nt < 7; ++nt) acc[mt][nt] = (f32x4){0.f, 0.f, 0.f, 0.f};

    // B-frag base byte offsets (tap 0,0): row = wp*14 + (ln>>3) + nt*2
    int nb[7];
    #pragma unroll
    for (int nt = 0; nt < 7; ++nt)
        nb[nt] = (((wp * 14 + (ln >> 3) + nt * 2) * 40 + (ln & 7) * 4 + quad)) * 16;

    // A-frag base byte offset: unit = cout_l*4 + quad, cout_l = wm*64+mt*16+ln
    const int abase = wm * 4096 + (ln * 4 + quad) * 16;   // + mt*1024 in loop

    // A staging: 512 units = 2 x 256; unit u -> cout_l = u>>2, sub = u&3
    const unsigned short* aspb = aggw + (size_t)(b * 9) * 65536 + ch * 32768;
    int aldsu[2], asrc[2];
    #pragma unroll
    for (int k = 0; k < 2; ++k) {
        const int u = tid + k * 256;
        aldsu[k] = u * 8;
        asrc[k] = (u >> 2) * 256 + (u & 3) * 8;
    }

    // B staging: 1200 units = 4 x 256 + 176 (k=4 predicated tid<176)
    const unsigned short* bsp[5];
    int bldsu[5];
    #pragma unroll
    for (int k = 0; k < 5; ++k) {
        int u = tid + k * 256; if (u > 1199) u = 1199;
        const int r = u / 40, rm = u - r * 40;
        const int c = rm >> 2, sub = rm & 3;
        bsp[k] = xpad + (size_t)(((b * HP + y0 + r) * HP + x0 + c)) * 256 + sub * 8;
        bldsu[k] = u * 8;
    }

    // prologue: stage A(tap=0, c0=0) -> bufA0, B(c0=0) -> bufB0
    #pragma unroll
    for (int k = 0; k < 2; ++k) gl_lds16(aspb + asrc[k], ldsA + aldsu[k]);
    #pragma unroll
    for (int k = 0; k < 4; ++k) gl_lds16(bsp[k], ldsB + bldsu[k]);
    if (tid < 176) gl_lds16(bsp[4], ldsB + bldsu[4]);
    __syncthreads();

    int pa = 0, pb = 0;
    #pragma unroll 1
    for (int c0 = 0; c0 < 256; c0 += 32) {
        #pragma unroll
        for (int tap = 0; tap < 9; ++tap) {
            // issue next-tap A-DMA into the other A buffer
            if (!(c0 == 224 && tap == 8)) {
                const int ntap = (tap == 8) ? 0 : tap + 1;
                const int nc0 = (tap == 8) ? c0 + 32 : c0;
                const unsigned short* srcA = aspb + ntap * 65536 + nc0;
                unsigned short* dA = ldsA + (pa ^ 1) * 4096;
                #pragma unroll
                for (int k = 0; k < 2; ++k) gl_lds16(srcA + asrc[k], dA + aldsu[k]);
            }
            // mid K-step: prefetch next c0's B slab into the other B buffer
            if (tap == 4 && c0 < 224) {
                unsigned short* dB = ldsB + (pb ^ 1) * 9600;
                #pragma unroll
                for (int k = 0; k < 4; ++k)
                    gl_lds16(bsp[k] + c0 + 32, dB + bldsu[k]);
                if (tid < 176) gl_lds16(bsp[4] + c0 + 32, dB + bldsu[4]);
            }
            // compute tap (ky = tap/3, kx = tap%3 -- static by unroll)
            const int ky = tap / 3, kx = tap % 3;
            const char* lA = (const char*)ldsA + pa * 8192;
            const char* lB = (const char*)ldsB + pb * 19200;
            bf16x8 a[4];
            #pragma unroll
            for (int mt = 0; mt < 4; ++mt)
                a[mt] = *(const bf16x8*)(lA + mt * 1024 + abase);
            #pragma unroll
            for (int nt = 0; nt < 7; ++nt) {
                const bf16x8 bf = *(const bf16x8*)(lB +
                    nb[nt] + (ky * 40 + kx * 4) * 16);
                #pragma unroll
                for (int mt = 0; mt < 4; ++mt)
                    acc[mt][nt] = __builtin_amdgcn_mfma_f32_16x16x32_bf16(
                        a[mt], bf, acc[mt][nt], 0, 0, 0);
            }
            __syncthreads();
            pa ^= 1;
        }
        pb ^= 1;
    }

    // epilogue: C/D layout col(n)=lane&15 -> pixel, row(m)=quad*4+reg -> cout
    #pragma unroll
    for (int mt = 0; mt < 4; ++mt) {
        #pragma unroll
        for (int nt = 0; nt < 7; ++nt) {
            const int yy = y0 + wp * 14 + (ln >> 3) + nt * 2;
            const int xx = x0 + (ln & 7);
            #pragma unroll
            for (int r = 0; r < 4; ++r) {
                const int cout = ch * 128 + wm * 64 + mt * 16 + quad * 4 + r;
                out[(size_t)(((b * 256 + cout) * HH + yy)) * HH + xx] = acc[mt][nt][r];
            }
        }
    }
}

// ---------------------------------------------------------------------------
extern "C" void kernel_launch(void* const* d_in, const int* in_sizes, int n_in,
                              void* d_out, int out_size, void* d_ws, size_t ws_size,
                              hipStream_t stream) {
    const float* x      = (const float*)d_in[0];
    const float* weight = (const float*)d_in[1];
    const float* am     = (const float*)d_in[2];
    const float* w1     = (const float*)d_in[3];
    const float* w2     = (const float*)d_in[4];
    const float* b2     = (const float*)d_in[5];
    float* out = (float*)d_out;
    char* ws = (char*)d_ws;

    float* s             = (float*)(ws + OFF_S);
    float* attn          = (float*)(ws + OFF_ATTN);
    float* wal           = (float*)(ws + OFF_WAL);
    unsigned short* aggw = (unsigned short*)(ws + OFF_AGGW);
    unsigned short* xpad = (unsigned short*)(ws + OFF_XPAD);

    hipMemsetAsync(s, 0, BATCH * 256 * sizeof(float), stream);
    xprep_kernel<<<dim3(28, 2, BATCH), 256, 0, stream>>>(x, xpad, s);
    attn_kernel<<<BATCH, 256, 0, stream>>>(s, w1, w2, b2, attn);
    align_kernel<<<dim3(18, 4, NEXP), 256, 0, stream>>>(am, weight, wal);
    agg_kernel<<<576, 256, 0, stream>>>(wal, attn, aggw);
    conv_kernel<<<896, 256, 0, stream>>>(xpad, aggw, out);
}